// Round 10
// baseline (89.763 us; speedup 1.0000x reference)
//
#include <hip/hip_runtime.h>
#include <hip/hip_bf16.h>

// Problem constants (reference: B=2, S=2048, D=1024, H=16, HD=64)
constexpr int Bb = 2, Ss = 2048, Dd = 1024, Hh = 16, HD = 64;
constexpr int Mrows = Bb * Ss;                 // 4096
constexpr float QSCALE = 0.125f * 1.44269504088896f;  // 1/sqrt(HD) * log2(e), folded into Q
constexpr size_t CTX_ELEMS = (size_t)Bb * Hh * Ss * HD;   // 4194304

typedef __attribute__((ext_vector_type(8)))  short        short8;
typedef __attribute__((ext_vector_type(4)))  float        floatx4;
typedef __attribute__((ext_vector_type(16))) float        floatx16;
typedef __attribute__((ext_vector_type(4)))  unsigned int uintx4;
typedef __attribute__((ext_vector_type(8)))  __bf16       bf16x8;

#define DEVI __device__ __forceinline__

DEVI unsigned short f2bf(float f) {
  union { float f; unsigned u; } x; x.f = f;
  return (unsigned short)((x.u + 0x7fffu + ((x.u >> 16) & 1u)) >> 16);   // RNE
}
DEVI float fexp2(float x) {
#if __has_builtin(__builtin_amdgcn_exp2f)
  return __builtin_amdgcn_exp2f(x);
#else
  return __expf(x * 0.6931471805599453f);
#endif
}
DEVI unsigned int cvtpk(float lo, float hi) {
  unsigned int r;
  asm("v_cvt_pk_bf16_f32 %0, %1, %2" : "=v"(r) : "v"(lo), "v"(hi));
  return r;
}

// workspace layout (bf16-elem units):  W bf16 (3*WE) | Q | K | V^T (3*XE)
constexpr size_t XE = (size_t)Mrows * Dd;      // 4M per projection output
constexpr size_t WE = (size_t)Dd * Dd;         // 1M per W tensor
constexpr size_t OFF_O = 3 * WE;               // outputs after converted W

// ---------------------------------------------------------------------------
// fp32 -> bf16 conversion of the three weight matrices only (12.6 MB read).
// ---------------------------------------------------------------------------
__global__ __launch_bounds__(256) void convert_w(
    const float* __restrict__ wq, const float* __restrict__ wk, const float* __restrict__ wv,
    unsigned short* __restrict__ dst)
{
  const int sel = blockIdx.y;
  const float* src = sel == 0 ? wq : sel == 1 ? wk : wv;
  unsigned short* d = dst + (size_t)sel * WE;
  const size_t stride = (size_t)gridDim.x * blockDim.x;
  for (size_t i = (size_t)blockIdx.x * blockDim.x + threadIdx.x; i < WE / 8; i += stride) {
    const floatx4 a = *(const floatx4*)(src + i * 8);
    const floatx4 b = *(const floatx4*)(src + i * 8 + 4);
    uintx4 o;
    o[0] = cvtpk(a[0], a[1]); o[1] = cvtpk(a[2], a[3]);
    o[2] = cvtpk(b[0], b[1]); o[3] = cvtpk(b[2], b[3]);
    *(uintx4*)(d + i * 8) = o;
  }
}

// ---------------------------------------------------------------------------
// Shared GEMM epilogue (16x16 layout).
// ---------------------------------------------------------------------------
template<bool SWAP>
DEVI void store_out(floatx4 (&acc)[4][4], const float* __restrict__ bias,
                    unsigned short* __restrict__ out, float oscale,
                    int bm, int bn, int wm, int wn, int lrow, int lg)
{
  if constexpr (!SWAP) {
    #pragma unroll
    for (int ni = 0; ni < 4; ++ni) {
      const int gcol = bn * 128 + wn + ni * 16 + lrow;
      const float bval = bias[gcol];
      const int h = gcol >> 6, hd = gcol & 63;
      #pragma unroll
      for (int mi = 0; mi < 4; ++mi)
        #pragma unroll
        for (int r = 0; r < 4; ++r) {
          const int grow = bm * 128 + wm + mi * 16 + lg * 4 + r;   // = b*S + s
          const int b = grow >> 11, s = grow & 2047;
          out[(((size_t)(b * Hh + h) * Ss + s) << 6) + hd] = f2bf((acc[mi][ni][r] + bval) * oscale);
        }
    }
  } else {
    #pragma unroll
    for (int ni = 0; ni < 4; ++ni)
      #pragma unroll
      for (int r = 0; r < 4; ++r) {
        const int n = bn * 128 + wn + ni * 16 + lg * 4 + r;
        const float bval = bias[n];
        #pragma unroll
        for (int mi = 0; mi < 4; ++mi) {
          const int m = bm * 128 + wm + mi * 16 + lrow;
          out[(size_t)n * Mrows + m] = f2bf(acc[mi][ni][r] + bval);
        }
      }
  }
}

// ---------------------------------------------------------------------------
// Mixed GEMM core: A = X fp32 (reg-staged, cvt_pk -> swizzled ds_write),
// B = W bf16 (global_load_lds 16B).  BK=64, XOR-swizzled LDS both sides.
// Next A-loads issued after the staging barrier -> overlap with MFMA (T14).
// ---------------------------------------------------------------------------
DEVI void gload16(const unsigned short* g, unsigned short* l) {
  __builtin_amdgcn_global_load_lds(
      (const __attribute__((address_space(1))) unsigned int*)g,
      (__attribute__((address_space(3))) unsigned int*)l, 16, 0, 0);
}

template<bool SWAP>
DEVI void gemm_core_mixed(const float* __restrict__ X,
                          const unsigned short* __restrict__ W,
                          const float* __restrict__ bias,
                          unsigned short* __restrict__ out, float oscale,
                          unsigned short* As, unsigned short* Bs, int bm, int bn)
{
  const int t = threadIdx.x, wid = t >> 6, lane = t & 63;
  const int lrow = lane & 15, lg = lane >> 4;
  const int wm = (wid >> 1) * 64, wn = (wid & 1) * 64;

  // --- A staging geometry (fp32 source): thread t covers rows {ar, ar+64},
  //     cols (t&3)*16 .. +16 of the 128x64 tile. ---
  const int ar = t >> 2;                  // 0..63
  const int acb = (t & 3) * 16;           // col base (fp32 elems)
  const float* gAbase = X + (size_t)(bm * 128 + ar) * Dd + acb;

  // --- B staging: per wave, 4 x gload16; pre-swizzled source chunk. ---
  const int srow = lane >> 3;             // 0..7
  const int gch  = (lane & 7) ^ srow;     // swizzled source chunk
  const unsigned short* gB = W + (size_t)(bn * 128 + wid * 32 + srow) * Dd + gch * 8;
  unsigned short* lB = Bs + wid * 4 * 512;

  floatx4 ra[2][4];                       // staged A fp32 (single buffer)
  auto loadA = [&](int k0) {
    #pragma unroll
    for (int i = 0; i < 2; ++i)
      #pragma unroll
      for (int j = 0; j < 4; ++j)
        ra[i][j] = *(const floatx4*)(gAbase + (size_t)i * 64 * Dd + k0 + j * 4);
  };
  auto writeA = [&]() {
    #pragma unroll
    for (int i = 0; i < 2; ++i) {
      const int row = ar + i * 64;
      #pragma unroll
      for (int j2 = 0; j2 < 2; ++j2) {    // 16B chunk of 8 bf16
        const floatx4 a = ra[i][2 * j2], b = ra[i][2 * j2 + 1];
        uintx4 w;
        w[0] = cvtpk(a[0], a[1]); w[1] = cvtpk(a[2], a[3]);
        w[2] = cvtpk(b[0], b[1]); w[3] = cvtpk(b[2], b[3]);
        const int cc = (acb >> 3) + j2;   // chunk index 0..7
        *(uintx4*)&As[row * 64 + ((cc ^ (row & 7)) << 3)] = w;
      }
    }
  };

  floatx4 acc[4][4];
  #pragma unroll
  for (int i = 0; i < 4; ++i)
    #pragma unroll
    for (int j = 0; j < 4; ++j) acc[i][j] = 0.0f;

  loadA(0);

  for (int k0 = 0; k0 < Dd; k0 += 64) {
    __syncthreads();                      // previous tile's fragment reads done
    writeA();                             // waits on A loads implicitly
    #pragma unroll
    for (int j = 0; j < 4; ++j)
      gload16(gB + (size_t)j * 8 * Dd + k0, lB + j * 512);
    __syncthreads();                      // A writes + B gload visible
    if (k0 + 64 < Dd) loadA(k0 + 64);     // next A loads overlap MFMA

    #pragma unroll
    for (int kf = 0; kf < 2; ++kf) {
      bf16x8 af[4], bf[4];
      #pragma unroll
      for (int mi = 0; mi < 4; ++mi) {
        const int row = wm + mi * 16 + lrow;
        const int ch  = ((kf << 2) | lg) ^ (lrow & 7);
        af[mi] = __builtin_bit_cast(bf16x8, *(const short8*)&As[row * 64 + (ch << 3)]);
      }
      #pragma unroll
      for (int ni = 0; ni < 4; ++ni) {
        const int row = wn + ni * 16 + lrow;
        const int ch  = ((kf << 2) | lg) ^ (lrow & 7);
        bf[ni] = __builtin_bit_cast(bf16x8, *(const short8*)&Bs[row * 64 + (ch << 3)]);
      }
      #pragma unroll
      for (int mi = 0; mi < 4; ++mi)
        #pragma unroll
        for (int ni = 0; ni < 4; ++ni) {
          if constexpr (SWAP)
            acc[mi][ni] = __builtin_amdgcn_mfma_f32_16x16x32_bf16(bf[ni], af[mi], acc[mi][ni], 0, 0, 0);
          else
            acc[mi][ni] = __builtin_amdgcn_mfma_f32_16x16x32_bf16(af[mi], bf[ni], acc[mi][ni], 0, 0, 0);
        }
    }
  }
  store_out<SWAP>(acc, bias, out, oscale, bm, bn, wm, wn, lrow, lg);
}

__global__ __launch_bounds__(256, 3) void qkv_gemm(
    const float* __restrict__ q, const float* __restrict__ k, const float* __restrict__ v,
    const unsigned short* __restrict__ wbf,
    const float* __restrict__ bq, const float* __restrict__ bk, const float* __restrict__ bv,
    unsigned short* __restrict__ outbase)
{
  __shared__ __align__(16) unsigned short As[128 * 64];   // 16 KB each
  __shared__ __align__(16) unsigned short Bs[128 * 64];

  // XCD-bijective swizzle over 768 blocks (96 contiguous per XCD).
  const int id  = blockIdx.y * 256 + blockIdx.x;
  const int swz = (id & 7) * 96 + (id >> 3);
  const int sel = swz >> 8;                  // 0..2 (Q,K,V)
  const int bx  = swz & 255;
  const int bm = bx >> 3, bn = bx & 7;

  const float* X = sel == 0 ? q : sel == 1 ? k : v;
  const unsigned short* W = wbf + (size_t)sel * WE;
  const float* bias = sel == 0 ? bq : sel == 1 ? bk : bv;
  unsigned short* out = outbase + (size_t)sel * XE;

  if (sel == 2) gemm_core_mixed<true >(X, W, bias, out, 1.0f, As, Bs, bm, bn);
  else          gemm_core_mixed<false>(X, W, bias, out, sel == 0 ? QSCALE : 1.0f, As, Bs, bm, bn);
}

// ---------------------------------------------------------------------------
// Flash attention, 8-wave in-block kv-split (UNCHANGED from round 9).
// Block = 512 threads: waves 0-3 do kv[0,1024), waves 4-7 kv[1024,2048) for
// the SAME 128 q-rows.  64 KB LDS -> 2 blocks/CU, 16 waves/CU.
// Epilogue combines halves through an LDS overlay; no global partials.
// permlane32_swap: a keeps lo lanes, a_hi <- b_lo; b_lo <- a_hi, b keeps hi.
// ---------------------------------------------------------------------------
__global__ __launch_bounds__(512, 4) void attn_fwd8(
    const unsigned short* __restrict__ Qw, const unsigned short* __restrict__ Kw,
    const unsigned short* __restrict__ Vw, float* __restrict__ out)
{
  __shared__ __align__(16) char smemRaw[65536];
  unsigned short* KsB = (unsigned short*)smemRaw;             // [kh][buf][64*64]
  unsigned short* VtB = (unsigned short*)(smemRaw + 32768);   // [kh][buf][64*64]
  float* ctxL  = (float*)smemRaw;                             // epilogue overlay (32 KB)
  float* lsumL = (float*)(smemRaw + 32768);                   // epilogue overlay

  // XCD-bijective swizzle: 512 blocks -> 64-contiguous per XCD.
  const int id  = blockIdx.y * 16 + blockIdx.x;
  const int swz = (id & 7) * 64 + (id >> 3);
  const int qb  = swz & 15, bh = swz >> 4;
  const int b   = bh >> 4, h = bh & 15;

  const int t = threadIdx.x, wid8 = t >> 6, lane = t & 63;
  const int kh = wid8 >> 2, wid = wid8 & 3;    // kv-half, wave-within-half
  const int l31 = lane & 31, hi = lane >> 5;
  const int kvbase = kh << 10;
  const unsigned short* Qb = Qw + (size_t)bh * (Ss * HD);
  const unsigned short* Kb = Kw + (size_t)bh * (Ss * HD);
  const unsigned short* Vg = Vw + (size_t)(h * 64) * Mrows + b * Ss;   // row=hd
  const int q0 = qb * 128 + wid * 32;

  // Q B-fragments: lane holds Q[q=l31][hd = hs*16 + hi*8 + j]
  bf16x8 qf[4];
  #pragma unroll
  for (int hs = 0; hs < 4; ++hs)
    qf[hs] = __builtin_bit_cast(bf16x8,
        *(const short8*)(Qb + (size_t)(q0 + l31) * 64 + hs * 16 + hi * 8));

  floatx16 ctx[2];
  ctx[0] = 0.0f; ctx[1] = 0.0f;
  float lsumv = 0.0f;                        // per-lane column sum

  // Staging: wave (kh,wid) covers rows wid*16 .. wid*16+15 of its half's tile.
  const int rl = lane >> 3;                  // 0..7 within 8-row group
  const int cs = (lane & 7) ^ rl;            // pre-swizzled source chunk
  auto stage = [&](int T) {                  // tile T (0..15) -> buf T&1 of half kh
    const int kv0 = kvbase + T * 64;
    unsigned short* Kd = KsB + (size_t)(kh * 2 + (T & 1)) * 4096;
    unsigned short* Vd = VtB + (size_t)(kh * 2 + (T & 1)) * 4096;
    #pragma unroll
    for (int i = 0; i < 2; ++i) {
      const int row = wid * 16 + i * 8 + rl;
      gload16(Kb + (size_t)(kv0 + row) * 64 + cs * 8, Kd + (wid * 16 + i * 8) * 64);
      gload16(Vg + (size_t)row * Mrows + kv0 + cs * 8, Vd + (wid * 16 + i * 8) * 64);
    }
  };

  stage(0);

  for (int it = 0; it < 16; ++it) {
    const int cur = it & 1;
    __syncthreads();                         // staged tile visible; prev buf free
    if (it + 1 < 16) stage(it + 1);
    const unsigned short* Kc = KsB + (size_t)(kh * 2 + cur) * 4096;
    const unsigned short* Vc = VtB + (size_t)(kh * 2 + cur) * 4096;

    #pragma unroll
    for (int kvb = 0; kvb < 2; ++kvb) {
      floatx16 s = 0.0f;
      __builtin_amdgcn_s_setprio(1);
      #pragma unroll
      for (int hs = 0; hs < 4; ++hs) {
        const int ch = ((hs << 1) | hi) ^ (l31 & 7);
        const bf16x8 kf = __builtin_bit_cast(bf16x8,
            *(const short8*)&Kc[(kvb * 32 + l31) * 64 + (ch << 3)]);
        s = __builtin_amdgcn_mfma_f32_32x32x16_bf16(kf, qf[hs], s, 0, 0, 0);
      }
      __builtin_amdgcn_s_setprio(0);

      float p[16];
      #pragma unroll
      for (int r = 0; r < 16; ++r) { p[r] = fexp2(s[r]); lsumv += p[r]; }
      unsigned int c[8];
      #pragma unroll
      for (int i = 0; i < 8; ++i)
        asm("v_cvt_pk_bf16_f32 %0, %1, %2" : "=v"(c[i]) : "v"(p[2 * i]), "v"(p[2 * i + 1]));

      #pragma unroll
      for (int ks2 = 0; ks2 < 2; ++ks2) {
        unsigned int w0 = c[4 * ks2 + 0], w2 = c[4 * ks2 + 2];
        unsigned int w1 = c[4 * ks2 + 1], w3 = c[4 * ks2 + 3];
        asm("v_permlane32_swap_b32 %0, %1" : "+v"(w0), "+v"(w2));
        asm("v_permlane32_swap_b32 %0, %1" : "+v"(w1), "+v"(w3));
        uintx4 paw; paw[0] = w0; paw[1] = w1; paw[2] = w2; paw[3] = w3;
        const bf16x8 pa = __builtin_bit_cast(bf16x8, paw);

        const int ks = kvb * 2 + ks2;        // 16-kv step within tile
        __builtin_amdgcn_s_setprio(1);
        #pragma unroll
        for (int nb = 0; nb < 2; ++nb) {
          const int ch = ((ks << 1) | hi) ^ (l31 & 7);
          const bf16x8 vf = __builtin_bit_cast(bf16x8,
              *(const short8*)&Vc[(nb * 32 + l31) * 64 + (ch << 3)]);
          ctx[nb] = __builtin_amdgcn_mfma_f32_32x32x16_bf16(pa, vf, ctx[nb], 0, 0, 0);
        }
        __builtin_amdgcn_s_setprio(0);
      }
    }
  }

  // ---- lsum hi-half combine (within wave). Partner value: sb (hi=0) / sa (hi=1).
  float sa = lsumv, sb = lsumv;
  asm("v_permlane32_swap_b32 %0, %1" : "+v"(sa), "+v"(sb));
  const float tot = lsumv + (hi ? sa : sb);   // this half's full column sum, q = q0+l31

  // ---- in-block kv-half combine via LDS overlay ----
  __syncthreads();                            // all waves done reading KsB/VtB
  if (kh == 1) {
    #pragma unroll
    for (int r = 0; r < 16; ++r)
      #pragma unroll
      for (int nb = 0; nb < 2; ++nb)
        ctxL[(nb * 16 + r) * 256 + wid * 64 + lane] = ctx[nb][r];   // lane-contiguous
    if (hi == 0) lsumL[wid * 32 + l31] = tot;
  }
  __syncthreads();
  if (kh == 0) {
    if (hi == 0) lsumL[128 + wid * 32 + l31] = tot + lsumL[wid * 32 + l31];
    #pragma unroll
    for (int r = 0; r < 16; ++r) {
      const int wr = (r & 3) + 8 * (r >> 2) + 4 * hi;
      const float inv = 1.0f / lsumL[128 + wid * 32 + wr];
      const int qrow = q0 + wr;
      #pragma unroll
      for (int nb = 0; nb < 2; ++nb) {
        const int hd = nb * 32 + l31;
        const float val = (ctx[nb][r] + ctxL[(nb * 16 + r) * 256 + wid * 64 + lane]) * inv;
        out[((size_t)bh * Ss + qrow) * 64 + hd] = val;                             // context
        out[CTX_ELEMS + (((size_t)(b * Ss + qrow)) << 10) + (h << 6) + hd] = val;  // attn_output
      }
    }
  }
}

// ---------------------------------------------------------------------------
extern "C" void kernel_launch(void* const* d_in, const int* in_sizes, int n_in,
                              void* d_out, int out_size, void* d_ws, size_t ws_size,
                              hipStream_t stream) {
  const float* q  = (const float*)d_in[0];
  const float* k  = (const float*)d_in[1];
  const float* v  = (const float*)d_in[2];
  const float* wq = (const float*)d_in[3];
  const float* bq = (const float*)d_in[4];
  const float* wk = (const float*)d_in[5];
  const float* bk = (const float*)d_in[6];
  const float* wv = (const float*)d_in[7];
  const float* bv = (const float*)d_in[8];
  unsigned short* ws = (unsigned short*)d_ws;
  float* out = (float*)d_out;

  unsigned short* wsW = ws;            // converted weights (3*WE)
  unsigned short* wsO = ws + OFF_O;    // Q | K | V^T outputs (3*XE)

  convert_w<<<dim3(64, 3), 256, 0, stream>>>(wq, wk, wv, wsW);
  qkv_gemm<<<dim3(256, 3), 256, 0, stream>>>(q, k, v, wsW, bq, bk, bv, wsO);
  attn_fwd8<<<dim3(16, 32), 512, 0, stream>>>(wsO, wsO + XE, wsO + 2 * XE, out);
}